// Round 9
// baseline (122.663 us; speedup 1.0000x reference)
//
#include <hip/hip_runtime.h>

typedef unsigned short u16;
typedef unsigned int u32;
typedef __attribute__((ext_vector_type(8))) short bf16x8;
typedef __attribute__((ext_vector_type(4))) float f32x4;

#define NUM_OPS 8
#define M_DIM 4096   // B*T
#define K_DIM 1024
#define N_DIM 1024
#define KT 32        // k-tiles of 32
// Fragment-tiled operands: 1KB chunks = 16 rows x 32 k; slot l (16B) holds
// row (l&15), k=(l>>4)*8+j  == exact MFMA A/B fragment lane order.
// chunk index = rowtile*32 + ktile.

// ---- helpers ----------------------------------------------------------

__device__ __forceinline__ u16 f2b(float f) {
  union { float f; u32 u; } v; v.f = f;
  u32 r = v.u + 0x7fffu + ((v.u >> 16) & 1u);  // RNE
  return (u16)(r >> 16);
}

__device__ __forceinline__ u32 pk2(float a, float b) {  // bf16(a) | bf16(b)<<16
  return (u32)f2b(a) | ((u32)f2b(b) << 16);
}

__device__ __forceinline__ int compute_idx(const float* __restrict__ logits,
                                           const float* __restrict__ u) {
  int best = 0; float bv = -3.4e38f;
#pragma unroll
  for (int i = 0; i < NUM_OPS; ++i) {
    float v = logits[i] - logf(-logf(u[i]));  // logits + gumbel
    if (v > bv) { bv = v; best = i; }
  }
  return best;
}

// ---- prep: x -> xb (frag-tiled bf16), W[idx] -> wt (frag-tiled bf16) ----
// (unchanged since R5 — verified)
__global__ void prep_kernel(const float* __restrict__ x, const float* __restrict__ W,
                            const float* __restrict__ logits, const float* __restrict__ u,
                            u16* __restrict__ xb, u16* __restrict__ wt) {
  const int tid = threadIdx.x;
  const int bid = blockIdx.x;
  if (bid < 2048) {
    const int chunk = bid * 4 + (tid >> 6), l = tid & 63;
    const int mtile = chunk >> 5, ktile = chunk & 31;
    const float* src = x + (size_t)(mtile * 16 + (l & 15)) * K_DIM
                         + ktile * 32 + (l >> 4) * 8;
    float4 f0 = *(const float4*)(src);
    float4 f1 = *(const float4*)(src + 4);
    uint4 p;
    p.x = pk2(f0.x, f0.y); p.y = pk2(f0.z, f0.w);
    p.z = pk2(f1.x, f1.y); p.w = pk2(f1.z, f1.w);
    *(uint4*)(xb + (size_t)chunk * 512 + l * 8) = p;
  } else {
    __shared__ u16 t[64][66];  // [k][n], +2 pad
    const int wb = bid - 2048;
    const int kt = wb >> 4, nt = wb & 15;   // 64x64 tile of W[k][n]
    const int idx = compute_idx(logits, u);
    const float* Wi = W + (size_t)idx * K_DIM * N_DIM;
#pragma unroll
    for (int it = 0; it < 16; ++it) {
      int i = it * 256 + tid;
      int r = i >> 6, c = i & 63;
      t[r][c] = f2b(Wi[(size_t)(kt * 64 + r) * N_DIM + nt * 64 + c]);
    }
    __syncthreads();
#pragma unroll
    for (int it = 0; it < 2; ++it) {
      int s = it * 256 + tid;
      int c = s >> 6, l = s & 63;
      int ntl = c & 3, ktl = c >> 2;
      int kb = ktl * 32 + (l >> 4) * 8, nn = ntl * 16 + (l & 15);
      uint4 p;
      p.x = (u32)t[kb + 0][nn] | ((u32)t[kb + 1][nn] << 16);
      p.y = (u32)t[kb + 2][nn] | ((u32)t[kb + 3][nn] << 16);
      p.z = (u32)t[kb + 4][nn] | ((u32)t[kb + 5][nn] << 16);
      p.w = (u32)t[kb + 6][nn] | ((u32)t[kb + 7][nn] << 16);
      int chunk = (nt * 4 + ntl) * 32 + (kt * 2 + ktl);
      *(uint4*)(wt + (size_t)chunk * 512 + l * 8) = p;
    }
  }
}

// ---- GEMM: out = x * W[idx] + b[idx] — NO LDS, NO BARRIERS --------------
// 1024 waves (grid 256 x 4 waves), each owns a 64x64 output tile.
// Fragments load DIRECTLY global->VGPR (frag-tiled operands: lane L reads
// chunk*512 + L*8, a coalesced global_load_dwordx4). Register double-buffer,
// k+1 loads issued before k's MFMAs: compiler pipelines on fine vmcnt(N) —
// no s_barrier / vmcnt(0) drain anywhere in the K-loop.
__global__ __launch_bounds__(256) void gemm_kernel(
    const u16* __restrict__ xb, const u16* __restrict__ wt,
    const float* __restrict__ bvec, const float* __restrict__ logits,
    const float* __restrict__ u, float* __restrict__ out) {
  const int tid = threadIdx.x;
  const int w = tid >> 6, L = tid & 63;
  const int bid = blockIdx.x;
  // XCD swizzle: XCD x=bid&7 covers m-tiles [8x,8x+8) x all n -> per-XCD
  // working set = 1MB xb slab + 2MB wt <= 4MB L2.
  const int x7 = bid & 7, r = bid >> 3;      // r in [0,32)
  const int mt = x7 * 8 + (r >> 2);          // 64-row m-tile, [0,64)
  const int nt = (r & 3) * 4 + w;            // 64-col n-tile, [0,16)

  // 8 fragment streams: A m-frag-tiles mt*4+f, B n-frag-tiles nt*4+f
  const u16* pa[4];
  const u16* pb[4];
#pragma unroll
  for (int f = 0; f < 4; ++f) {
    pa[f] = xb + ((size_t)(mt * 4 + f) * 32) * 512 + L * 8;
    pb[f] = wt + ((size_t)(nt * 4 + f) * 32) * 512 + L * 8;
  }

  f32x4 acc[4][4] = {};
  bf16x8 af[2][4], bf[2][4];

  // preload k-tile 0
#pragma unroll
  for (int f = 0; f < 4; ++f) {
    af[0][f] = *(const bf16x8*)(pa[f]);
    bf[0][f] = *(const bf16x8*)(pb[f]);
  }

#pragma unroll
  for (int kt = 0; kt < KT; ++kt) {
    const int cur = kt & 1, nxt = cur ^ 1;
    if (kt + 1 < KT) {  // prefetch k+1 (in flight during MFMAs below)
      const int ko = (kt + 1) * 512;
#pragma unroll
      for (int f = 0; f < 4; ++f) {
        af[nxt][f] = *(const bf16x8*)(pa[f] + ko);
        bf[nxt][f] = *(const bf16x8*)(pb[f] + ko);
      }
    }
#pragma unroll
    for (int mf = 0; mf < 4; ++mf)
#pragma unroll
      for (int nf = 0; nf < 4; ++nf)
        acc[mf][nf] = __builtin_amdgcn_mfma_f32_16x16x32_bf16(
            af[cur][mf], bf[cur][nf], acc[mf][nf], 0, 0, 0);
  }

  // epilogue: C/D layout col=lane&15, row=(lane>>4)*4+reg
  const int idx = compute_idx(logits, u);
  const float* bi = bvec + (size_t)idx * N_DIM;
#pragma unroll
  for (int mf = 0; mf < 4; ++mf) {
    int row = mt * 64 + 16 * mf + (L >> 4) * 4;
#pragma unroll
    for (int nf = 0; nf < 4; ++nf) {
      int col = nt * 64 + 16 * nf + (L & 15);
      float bv = bi[col];
#pragma unroll
      for (int rr = 0; rr < 4; ++rr)
        out[(size_t)(row + rr) * N_DIM + col] = acc[mf][nf][rr] + bv;
    }
  }
}

// ---- launch -----------------------------------------------------------

extern "C" void kernel_launch(void* const* d_in, const int* in_sizes, int n_in,
                              void* d_out, int out_size, void* d_ws, size_t ws_size,
                              hipStream_t stream) {
  const float* x      = (const float*)d_in[0];
  const float* W      = (const float*)d_in[1];
  const float* bvec   = (const float*)d_in[2];
  const float* logits = (const float*)d_in[3];
  const float* u      = (const float*)d_in[4];
  float* out = (float*)d_out;

  u16* xb = (u16*)d_ws;                          // frag-tiled x, 8 MB
  u16* wt = (u16*)d_ws + (size_t)M_DIM * K_DIM;  // frag-tiled W[idx], 2 MB

  prep_kernel<<<2048 + 256, 256, 0, stream>>>(x, W, logits, u, xb, wt);
  gemm_kernel<<<256, 256, 0, stream>>>(xb, wt, bvec, logits, u, out);
}

// Round 10
// 114.176 us; speedup vs baseline: 1.0743x; 1.0743x over previous
//
#include <hip/hip_runtime.h>

typedef unsigned short u16;
typedef unsigned int u32;
typedef __attribute__((ext_vector_type(8))) short bf16x8;
typedef __attribute__((ext_vector_type(4))) float f32x4;

#define NUM_OPS 8
#define M_DIM 4096   // B*T
#define K_DIM 1024
#define N_DIM 1024
#define KT_PER_WAVE 16   // split-K=2: each wave covers 16 of 32 k-tiles
// Fragment-tiled operands: 1KB chunks = 16 rows x 32 k; slot l (16B) holds
// row (l&15), k=(l>>4)*8+j  == exact MFMA A/B fragment lane order.
// chunk index = rowtile*32 + ktile.

// ---- helpers ----------------------------------------------------------

__device__ __forceinline__ u16 f2b(float f) {
  union { float f; u32 u; } v; v.f = f;
  u32 r = v.u + 0x7fffu + ((v.u >> 16) & 1u);  // RNE
  return (u16)(r >> 16);
}

__device__ __forceinline__ u32 pk2(float a, float b) {  // bf16(a) | bf16(b)<<16
  return (u32)f2b(a) | ((u32)f2b(b) << 16);
}

__device__ __forceinline__ int compute_idx(const float* __restrict__ logits,
                                           const float* __restrict__ u) {
  int best = 0; float bv = -3.4e38f;
#pragma unroll
  for (int i = 0; i < NUM_OPS; ++i) {
    float v = logits[i] - logf(-logf(u[i]));  // logits + gumbel
    if (v > bv) { bv = v; best = i; }
  }
  return best;
}

// ---- prep: x -> xb (frag-tiled bf16), W[idx] -> wt (frag-tiled bf16) ----
// (unchanged since R5 — verified)
__global__ void prep_kernel(const float* __restrict__ x, const float* __restrict__ W,
                            const float* __restrict__ logits, const float* __restrict__ u,
                            u16* __restrict__ xb, u16* __restrict__ wt) {
  const int tid = threadIdx.x;
  const int bid = blockIdx.x;
  if (bid < 2048) {
    const int chunk = bid * 4 + (tid >> 6), l = tid & 63;
    const int mtile = chunk >> 5, ktile = chunk & 31;
    const float* src = x + (size_t)(mtile * 16 + (l & 15)) * K_DIM
                         + ktile * 32 + (l >> 4) * 8;
    float4 f0 = *(const float4*)(src);
    float4 f1 = *(const float4*)(src + 4);
    uint4 p;
    p.x = pk2(f0.x, f0.y); p.y = pk2(f0.z, f0.w);
    p.z = pk2(f1.x, f1.y); p.w = pk2(f1.z, f1.w);
    *(uint4*)(xb + (size_t)chunk * 512 + l * 8) = p;
  } else {
    __shared__ u16 t[64][66];  // [k][n], +2 pad
    const int wb = bid - 2048;
    const int kt = wb >> 4, nt = wb & 15;   // 64x64 tile of W[k][n]
    const int idx = compute_idx(logits, u);
    const float* Wi = W + (size_t)idx * K_DIM * N_DIM;
#pragma unroll
    for (int it = 0; it < 16; ++it) {
      int i = it * 256 + tid;
      int r = i >> 6, c = i & 63;
      t[r][c] = f2b(Wi[(size_t)(kt * 64 + r) * N_DIM + nt * 64 + c]);
    }
    __syncthreads();
#pragma unroll
    for (int it = 0; it < 2; ++it) {
      int s = it * 256 + tid;
      int c = s >> 6, l = s & 63;
      int ntl = c & 3, ktl = c >> 2;
      int kb = ktl * 32 + (l >> 4) * 8, nn = ntl * 16 + (l & 15);
      uint4 p;
      p.x = (u32)t[kb + 0][nn] | ((u32)t[kb + 1][nn] << 16);
      p.y = (u32)t[kb + 2][nn] | ((u32)t[kb + 3][nn] << 16);
      p.z = (u32)t[kb + 4][nn] | ((u32)t[kb + 5][nn] << 16);
      p.w = (u32)t[kb + 6][nn] | ((u32)t[kb + 7][nn] << 16);
      int chunk = (nt * 4 + ntl) * 32 + (kt * 2 + ktl);
      *(uint4*)(wt + (size_t)chunk * 512 + l * 8) = p;
    }
  }
}

// ---- GEMM: out = x * W[idx] + b[idx] — no-barrier K-loop + split-K=2 ----
// 512 blocks x 4 waves = 2048 wave-tasks: (64 mt x 16 nt) tiles x 2 K-halves.
// 2 waves/SIMD (independent streams hide each other's load latency).
// Fragments stream DIRECTLY global->VGPR (coalesced dwordx4 from frag-tiled
// operands); triple-buffered regs, k+2 prefetch => ~2 iters of latency cover.
// NO LDS / NO barriers in the K-loop; one LDS exchange at the end combines
// the two K-halves.
__global__ __launch_bounds__(256, 2) void gemm_kernel(
    const u16* __restrict__ xb, const u16* __restrict__ wt,
    const float* __restrict__ bvec, const float* __restrict__ logits,
    const float* __restrict__ u, float* __restrict__ out) {
  __shared__ f32x4 xc[2 * 1024];  // 2 tiles x 1024 f32x4 = 32KB (epilogue only)

  const int tid = threadIdx.x;
  const int w = tid >> 6, L = tid & 63;
  const int bid = blockIdx.x;
  // XCD swizzle: XCD x=bid&7 covers mt in [8x,8x+8) x all nt -> per-XCD
  // working set = 1MB xb slab + 2MB wt <= 4MB L2.
  const int x7 = bid & 7, t = bid >> 3;  // t in [0,64)
  const int tl = w >> 1;                 // tile-local index 0/1
  const int ti = t * 2 + tl;             // [0,128) within XCD slab
  const int mt = x7 * 8 + (ti >> 4);     // [0,64) 64-row m-tile
  const int nt = ti & 15;                // [0,16) 64-col n-tile
  const int kh = w & 1;                  // K half (0: k-tiles 0..15, 1: 16..31)
  const int k0 = kh * KT_PER_WAVE;

  // 8 fragment streams, offset to this wave's K half
  const u16* pa[4];
  const u16* pb[4];
#pragma unroll
  for (int f = 0; f < 4; ++f) {
    pa[f] = xb + ((size_t)((mt * 4 + f) * 32 + k0)) * 512 + L * 8;
    pb[f] = wt + ((size_t)((nt * 4 + f) * 32 + k0)) * 512 + L * 8;
  }

  f32x4 acc[4][4] = {};
  bf16x8 af[3][4], bf[3][4];  // triple-buffered fragment regs

  // preload k-tiles 0 and 1
#pragma unroll
  for (int f = 0; f < 4; ++f) {
    af[0][f] = *(const bf16x8*)(pa[f]);
    bf[0][f] = *(const bf16x8*)(pb[f]);
  }
#pragma unroll
  for (int f = 0; f < 4; ++f) {
    af[1][f] = *(const bf16x8*)(pa[f] + 512);
    bf[1][f] = *(const bf16x8*)(pb[f] + 512);
  }

#pragma unroll
  for (int kt = 0; kt < KT_PER_WAVE; ++kt) {
    const int cur = kt % 3;
    if (kt + 2 < KT_PER_WAVE) {  // issue k+2 loads: ~2 iterations in flight
      const int nb_ = (kt + 2) % 3;
      const int ko = (kt + 2) * 512;
#pragma unroll
      for (int f = 0; f < 4; ++f) {
        af[nb_][f] = *(const bf16x8*)(pa[f] + ko);
        bf[nb_][f] = *(const bf16x8*)(pb[f] + ko);
      }
    }
#pragma unroll
    for (int mf = 0; mf < 4; ++mf)
#pragma unroll
      for (int nf = 0; nf < 4; ++nf)
        acc[mf][nf] = __builtin_amdgcn_mfma_f32_16x16x32_bf16(
            af[cur][mf], bf[cur][nf], acc[mf][nf], 0, 0, 0);
  }

  // ---- split-K combine: kh=1 wave dumps acc to LDS; kh=0 adds + stores ----
  if (kh == 1) {
#pragma unroll
    for (int mf = 0; mf < 4; ++mf)
#pragma unroll
      for (int nf = 0; nf < 4; ++nf)
        xc[tl * 1024 + (mf * 4 + nf) * 64 + L] = acc[mf][nf];
  }
  __syncthreads();
  if (kh == 0) {
    const int idx = compute_idx(logits, u);
    const float* bi = bvec + (size_t)idx * N_DIM;
#pragma unroll
    for (int mf = 0; mf < 4; ++mf) {
      int row = mt * 64 + 16 * mf + (L >> 4) * 4;
#pragma unroll
      for (int nf = 0; nf < 4; ++nf) {
        int col = nt * 64 + 16 * nf + (L & 15);
        float bv = bi[col];
        f32x4 o = acc[mf][nf] + xc[tl * 1024 + (mf * 4 + nf) * 64 + L];
#pragma unroll
        for (int r = 0; r < 4; ++r)
          out[(size_t)(row + r) * N_DIM + col] = o[r] + bv;
      }
    }
  }
}

// ---- launch -----------------------------------------------------------

extern "C" void kernel_launch(void* const* d_in, const int* in_sizes, int n_in,
                              void* d_out, int out_size, void* d_ws, size_t ws_size,
                              hipStream_t stream) {
  const float* x      = (const float*)d_in[0];
  const float* W      = (const float*)d_in[1];
  const float* bvec   = (const float*)d_in[2];
  const float* logits = (const float*)d_in[3];
  const float* u      = (const float*)d_in[4];
  float* out = (float*)d_out;

  u16* xb = (u16*)d_ws;                          // frag-tiled x, 8 MB
  u16* wt = (u16*)d_ws + (size_t)M_DIM * K_DIM;  // frag-tiled W[idx], 2 MB

  prep_kernel<<<2048 + 256, 256, 0, stream>>>(x, W, logits, u, xb, wt);
  gemm_kernel<<<512, 256, 0, stream>>>(xb, wt, bvec, logits, u, out);
}

// Round 11
// 106.855 us; speedup vs baseline: 1.1479x; 1.0685x over previous
//
#include <hip/hip_runtime.h>

typedef unsigned short u16;
typedef unsigned int u32;
typedef __attribute__((ext_vector_type(8))) short bf16x8;
typedef __attribute__((ext_vector_type(4))) float f32x4;

#define NUM_OPS 8
#define M_DIM 4096   // B*T
#define K_DIM 1024
#define N_DIM 1024
#define BK 64
#define KITERS (K_DIM / BK)   // 16
// Fragment-tiled operands: 1KB chunks = 16 rows x 32 k; slot l (16B) holds
// row (l&15), k=(l>>4)*8+j  == exact MFMA A/B fragment lane order.
// chunk index = rowtile*32 + ktile (ktile of 32).
// This is the R6 configuration — measured best (104.3 us total).

// ---- helpers ----------------------------------------------------------

__device__ __forceinline__ u16 f2b(float f) {
  union { float f; u32 u; } v; v.f = f;
  u32 r = v.u + 0x7fffu + ((v.u >> 16) & 1u);  // RNE
  return (u16)(r >> 16);
}

__device__ __forceinline__ u32 pk2(float a, float b) {  // bf16(a) | bf16(b)<<16
  return (u32)f2b(a) | ((u32)f2b(b) << 16);
}

__device__ __forceinline__ int compute_idx(const float* __restrict__ logits,
                                           const float* __restrict__ u) {
  int best = 0; float bv = -3.4e38f;
#pragma unroll
  for (int i = 0; i < NUM_OPS; ++i) {
    float v = logits[i] - logf(-logf(u[i]));  // logits + gumbel
    if (v > bv) { bv = v; best = i; }
  }
  return best;
}

// async global->LDS, 16B/lane
__device__ __forceinline__ void gld_lds16(const void* g, void* l) {
  __builtin_amdgcn_global_load_lds(
      (__attribute__((address_space(1))) void*)(g),
      (__attribute__((address_space(3))) void*)(unsigned)(unsigned long long)(l),
      16, 0, 0);
}

// ---- prep: x -> xb (frag-tiled bf16), W[idx] -> wt (frag-tiled bf16) ----
__global__ void prep_kernel(const float* __restrict__ x, const float* __restrict__ W,
                            const float* __restrict__ logits, const float* __restrict__ u,
                            u16* __restrict__ xb, u16* __restrict__ wt) {
  const int tid = threadIdx.x;
  const int bid = blockIdx.x;
  if (bid < 2048) {
    const int chunk = bid * 4 + (tid >> 6), l = tid & 63;
    const int mtile = chunk >> 5, ktile = chunk & 31;
    const float* src = x + (size_t)(mtile * 16 + (l & 15)) * K_DIM
                         + ktile * 32 + (l >> 4) * 8;
    float4 f0 = *(const float4*)(src);
    float4 f1 = *(const float4*)(src + 4);
    uint4 p;
    p.x = pk2(f0.x, f0.y); p.y = pk2(f0.z, f0.w);
    p.z = pk2(f1.x, f1.y); p.w = pk2(f1.z, f1.w);
    *(uint4*)(xb + (size_t)chunk * 512 + l * 8) = p;
  } else {
    __shared__ u16 t[64][66];  // [k][n], +2 pad
    const int wb = bid - 2048;
    const int kt = wb >> 4, nt = wb & 15;   // 64x64 tile of W[k][n]
    const int idx = compute_idx(logits, u);
    const float* Wi = W + (size_t)idx * K_DIM * N_DIM;
#pragma unroll
    for (int it = 0; it < 16; ++it) {
      int i = it * 256 + tid;
      int r = i >> 6, c = i & 63;
      t[r][c] = f2b(Wi[(size_t)(kt * 64 + r) * N_DIM + nt * 64 + c]);
    }
    __syncthreads();
#pragma unroll
    for (int it = 0; it < 2; ++it) {
      int s = it * 256 + tid;
      int c = s >> 6, l = s & 63;
      int ntl = c & 3, ktl = c >> 2;
      int kb = ktl * 32 + (l >> 4) * 8, nn = ntl * 16 + (l & 15);
      uint4 p;
      p.x = (u32)t[kb + 0][nn] | ((u32)t[kb + 1][nn] << 16);
      p.y = (u32)t[kb + 2][nn] | ((u32)t[kb + 3][nn] << 16);
      p.z = (u32)t[kb + 4][nn] | ((u32)t[kb + 5][nn] << 16);
      p.w = (u32)t[kb + 6][nn] | ((u32)t[kb + 7][nn] << 16);
      int chunk = (nt * 4 + ntl) * 32 + (kt * 2 + ktl);
      *(uint4*)(wt + (size_t)chunk * 512 + l * 8) = p;
    }
  }
}

// ---- GEMM: out = x * W[idx] + b[idx] -----------------------------------
// BM=64, BN=128, BK=64; 256 thr = 4 waves (2m x 2n), wave tile 32x64.
// Grid 512 = 2 blocks/CU: two INDEPENDENT barrier groups per CU -> 2
// waves/SIMD interleave (one computes while the other drains/stages).
// 24 chunks/iter staged via gld_lds16 (6/wave), dbuf, one barrier/iter.
__global__ __launch_bounds__(256) void gemm_kernel(
    const u16* __restrict__ xb, const u16* __restrict__ wt,
    const float* __restrict__ bvec, const float* __restrict__ logits,
    const float* __restrict__ u, float* __restrict__ out) {
  // unified chunk store: A chunks 0..7, B chunks 8..23 (24 KB per buf)
  __shared__ u16 sm[2][24 * 512];

  const int tid = threadIdx.x;
  const int w = tid >> 6, L = tid & 63;
  const int bid = blockIdx.x;
  const int mb = (bid & 7) * 8 + (bid >> 6);   // [0,64): XCD-local m-slabs
  const int nb = (bid >> 3) & 7;               // [0,8)

  // staging: wave w handles items 6w..6w+5; item<8 -> A chunk, else B
  const u16* gsrc[6];
  int lofs[6];
#pragma unroll
  for (int j = 0; j < 6; ++j) {
    int item = 6 * w + j;
    if (item < 8) {
      int mt = item >> 1, dk = item & 1;
      gsrc[j] = xb + ((size_t)((mb * 4 + mt) * 32 + dk)) * 512 + L * 8;
    } else {
      int t = item - 8, nt = t >> 1, dk = t & 1;
      gsrc[j] = wt + ((size_t)((nb * 8 + nt) * 32 + dk)) * 512 + L * 8;
    }
    lofs[j] = item * 512 + L * 8;
  }

  const int wm = w & 1, wn = w >> 1;
  int aoff[2][2], boff[4][2];
#pragma unroll
  for (int f = 0; f < 2; ++f)
#pragma unroll
    for (int dk = 0; dk < 2; ++dk)
      aoff[f][dk] = ((2 * wm + f) * 2 + dk) * 512 + L * 8;
#pragma unroll
  for (int t = 0; t < 4; ++t)
#pragma unroll
    for (int dk = 0; dk < 2; ++dk)
      boff[t][dk] = (8 + (4 * wn + t) * 2 + dk) * 512 + L * 8;

  f32x4 acc[2][4] = {};

  // prologue: stage k-iter 0 into buf 0
#pragma unroll
  for (int j = 0; j < 6; ++j) gld_lds16(gsrc[j], &sm[0][lofs[j]]);

  for (int kk = 0; kk < KITERS; ++kk) {
    const int cur = kk & 1, nxt = cur ^ 1;
    __syncthreads();  // drains own staging (vmcnt); all waves' chunks landed

    if (kk + 1 < KITERS) {
      const int ko = (kk + 1) * 1024;  // 2 ktiles per iter, 512 u16 each
#pragma unroll
      for (int j = 0; j < 6; ++j) gld_lds16(gsrc[j] + ko, &sm[nxt][lofs[j]]);
    }

    bf16x8 af[2][2], bf[4][2];
#pragma unroll
    for (int f = 0; f < 2; ++f)
#pragma unroll
      for (int dk = 0; dk < 2; ++dk)
        af[f][dk] = *(const bf16x8*)(&sm[cur][aoff[f][dk]]);
#pragma unroll
    for (int t = 0; t < 4; ++t)
#pragma unroll
      for (int dk = 0; dk < 2; ++dk)
        bf[t][dk] = *(const bf16x8*)(&sm[cur][boff[t][dk]]);
#pragma unroll
    for (int dk = 0; dk < 2; ++dk)
#pragma unroll
      for (int f = 0; f < 2; ++f)
#pragma unroll
        for (int t = 0; t < 4; ++t)
          acc[f][t] = __builtin_amdgcn_mfma_f32_16x16x32_bf16(
              af[f][dk], bf[t][dk], acc[f][t], 0, 0, 0);
    // no trailing barrier: buf[nxt] writers are gated by this iter's barrier
  }

  // epilogue: C/D layout col=lane&15, row=(lane>>4)*4+reg
  const int idx = compute_idx(logits, u);
  const float* bi = bvec + (size_t)idx * N_DIM;
#pragma unroll
  for (int f = 0; f < 2; ++f) {
    int row = mb * 64 + 32 * wm + 16 * f + (L >> 4) * 4;
#pragma unroll
    for (int t = 0; t < 4; ++t) {
      int col = nb * 128 + 64 * wn + 16 * t + (L & 15);
      float bv = bi[col];
#pragma unroll
      for (int r = 0; r < 4; ++r)
        out[(size_t)(row + r) * N_DIM + col] = acc[f][t][r] + bv;
    }
  }
}

// ---- launch -----------------------------------------------------------

extern "C" void kernel_launch(void* const* d_in, const int* in_sizes, int n_in,
                              void* d_out, int out_size, void* d_ws, size_t ws_size,
                              hipStream_t stream) {
  const float* x      = (const float*)d_in[0];
  const float* W      = (const float*)d_in[1];
  const float* bvec   = (const float*)d_in[2];
  const float* logits = (const float*)d_in[3];
  const float* u      = (const float*)d_in[4];
  float* out = (float*)d_out;

  u16* xb = (u16*)d_ws;                          // frag-tiled x, 8 MB
  u16* wt = (u16*)d_ws + (size_t)M_DIM * K_DIM;  // frag-tiled W[idx], 2 MB

  prep_kernel<<<2048 + 256, 256, 0, stream>>>(x, W, logits, u, xb, wt);
  gemm_kernel<<<512, 256, 0, stream>>>(xb, wt, bvec, logits, u, out);
}